// Round 14
// baseline (99.241 us; speedup 1.0000x reference)
//
#include <hip/hip_runtime.h>
#include <hip/hip_bf16.h>

// Problem constants (fixed by setup_inputs)
#define B 4
#define T 1024
#define D 512
#define U 32
#define WIN 64           // attention window (j in [t-32, t+31])
#define EPS 1e-7f

__device__ __forceinline__ float fast_tanh(float z) {
    const float ez = __expf(2.0f * z);
    return 1.0f - 2.0f / (ez + 1.0f);
}

__device__ __forceinline__ float bcast_lane(float v, int l) {
    return __int_as_float(__builtin_amdgcn_readlane(__float_as_int(v), l));
}

// ---------------------------------------------------------------------------
// Kernel A v5.1 (UNCHANGED from round 12 — single-variable discipline).
// Measured 12.5 us. XCD-chunk-aligned row mapping.
// ---------------------------------------------------------------------------
__global__ __launch_bounds__(512) void qk_kernel(
    const float* __restrict__ x, const float* __restrict__ Wt,
    const float* __restrict__ Wx, const float* __restrict__ bh,
    float* __restrict__ qk)
{
    __shared__ float W2[D][64];          // 128 KB: [d][0:32]=Wt, [32:64]=Wx

    const int tid  = threadIdx.x;
    const int lane = tid & 63;
    const int wv   = tid >> 6;           // 0..7
    const int bid  = blockIdx.x;
    const int r0   = (bid & 7) * 512 + (bid >> 3) * 16 + wv * 2;

    {
        const float4* Wt4 = (const float4*)Wt;
        const float4* Wx4 = (const float4*)Wx;
        #pragma unroll
        for (int i = 0; i < 8; ++i) {
            const int j  = i * 512 + tid;     // float4 index 0..4095
            const int d  = j >> 3;
            const int u0 = (j & 7) << 2;
            *(float4*)&W2[d][u0]      = Wt4[j];
            *(float4*)&W2[d][32 + u0] = Wx4[j];
        }
    }

    const float4* xr0 = (const float4*)(x + (size_t)(r0 + 0) * D);
    const float4* xr1 = (const float4*)(x + (size_t)(r0 + 1) * D);
    const float4 A0 = xr0[lane * 2], A1 = xr0[lane * 2 + 1];
    const float4 B0 = xr1[lane * 2], B1 = xr1[lane * 2 + 1];
    const float xa[8] = {A0.x, A0.y, A0.z, A0.w, A1.x, A1.y, A1.z, A1.w};
    const float xb[8] = {B0.x, B0.y, B0.z, B0.w, B1.x, B1.y, B1.z, B1.w};

    __syncthreads();

    const float bias = (lane < U) ? bh[lane] : 0.0f;
    float acc0 = bias, acc1 = bias;

    #pragma unroll
    for (int l = 0; l < 64; ++l) {
        #pragma unroll
        for (int r = 0; r < 8; ++r) {
            const float w  = W2[l * 8 + r][lane];
            const float s0 = bcast_lane(xa[r], l);
            const float s1 = bcast_lane(xb[r], l);
            acc0 = fmaf(s0, w, acc0);
            acc1 = fmaf(s1, w, acc1);
        }
    }

    qk[(size_t)(r0 + 0) * WIN + lane] = acc0;
    qk[(size_t)(r0 + 1) * WIN + lane] = acc1;
}

// ---------------------------------------------------------------------------
// Kernel B v5: LDS-STAGED x window. 256 blocks x 512 thr (8 waves, 1 blk/CU).
// Block = 32 t x one d-half. Stage x rows [t0-32, t0+64) x 256 floats (96 KB)
// into LDS once; phase 2 reads x ONLY from LDS (conflict-free ds_read_b128,
// ~12cyc throughput vs 200-900cyc global latency). Each wave scores its own
// 4 t's, weights stay in registers (no A[] LDS, single barrier). Global x
// traffic per block: 96 KB vs v3's 268 KB; latency moved off critical path.
// ---------------------------------------------------------------------------
__global__ __launch_bounds__(512) void attn_kernel(
    const float* __restrict__ x, const float* __restrict__ qk,
    const float* __restrict__ Wa, const float* __restrict__ ba,
    float* __restrict__ out)
{
    __shared__ float xs[96 * 256];       // 96 KB staged x window (d-half)

    const int tid  = threadIdx.x;
    const int lane = tid & 63;
    const int wq   = tid >> 6;                   // wave 0..7
    const int bid  = blockIdx.x;
    const int c    = bid & 7;                    // XCD
    const int rr   = bid >> 3;                   // 0..31
    const int g    = c * 16 + (rr >> 1);         // t-group 0..127 (XCD-chunked)
    const int dh   = rr & 1;                     // d-half
    const int g0   = g * 32;                     // global row base = b*T + t0
    const int b    = g0 >> 10;
    const int t0   = g0 & (T - 1);               // multiple of 32
    const int tq   = t0 + wq * 4;                // this wave's t-quad base

    const float* xh = x + (size_t)b * T * D + dh * (D / 2);

    // ---- stage 96 rows x 256 floats (clamped; OOB rows weight-0) ----
    #pragma unroll
    for (int i = 0; i < 12; ++i) {
        const int idx = i * 512 + tid;           // float4 idx 0..6143
        const int lr  = idx >> 6;                // local row 0..95
        const int c4  = idx & 63;                // float4 col
        int grow = t0 - 32 + lr;
        grow = (grow < 0) ? 0 : grow;
        grow = (grow > T - 1) ? (T - 1) : grow;
        *(float4*)&xs[lr * 256 + c4 * 4] =
            *(const float4*)(xh + (size_t)grow * D + c4 * 4);
    }

    // ---- phase 1: scores for tq..tq+3 (overlaps staging latency) ----
    float wgt[4];
    #pragma unroll
    for (int i = 0; i < 4; ++i) {
        const int tt = tq + i;
        const float* qrow = qk + (size_t)(b * T + tt) * WIN;
        const int jj = tt - 32 + lane;
        float e = 0.0f;
        if (jj >= 0 && jj < T) {
            const float* krow = qk + (size_t)(b * T + jj) * WIN + U;
            float acc = ba[0];
            #pragma unroll
            for (int i4 = 0; i4 < 8; ++i4) {
                const float4 kv = ((const float4*)krow)[i4];
                const float4 qv = ((const float4*)qrow)[i4];
                acc = fmaf(Wa[i4 * 4 + 0], fast_tanh(qv.x + kv.x), acc);
                acc = fmaf(Wa[i4 * 4 + 1], fast_tanh(qv.y + kv.y), acc);
                acc = fmaf(Wa[i4 * 4 + 2], fast_tanh(qv.z + kv.z), acc);
                acc = fmaf(Wa[i4 * 4 + 3], fast_tanh(qv.w + kv.w), acc);
            }
            e = __expf(acc);
        }
        float s = e;
        #pragma unroll
        for (int off = 32; off > 0; off >>= 1)
            s += __shfl_xor(s, off);
        wgt[i] = e / (s + EPS);                  // lane j holds a_j for t=tt
    }
    __syncthreads();                             // staging complete

    // ---- phase 2: 67 LDS rows, 4 outputs ----
    float4 v0 = make_float4(0.f,0.f,0.f,0.f), v1 = v0, v2 = v0, v3 = v0;
    const float* xw = &xs[(size_t)wq * 4 * 256]; // wave's local row base

    #pragma unroll
    for (int m = 0; m < 67; ++m) {
        const float4 xv = *(const float4*)&xw[m * 256 + lane * 4];
        if (m <= 63) {
            const float a0 = bcast_lane(wgt[0], m);
            v0.x = fmaf(a0, xv.x, v0.x); v0.y = fmaf(a0, xv.y, v0.y);
            v0.z = fmaf(a0, xv.z, v0.z); v0.w = fmaf(a0, xv.w, v0.w);
        }
        if (m >= 1 && m <= 64) {
            const float a1 = bcast_lane(wgt[1], m - 1);
            v1.x = fmaf(a1, xv.x, v1.x); v1.y = fmaf(a1, xv.y, v1.y);
            v1.z = fmaf(a1, xv.z, v1.z); v1.w = fmaf(a1, xv.w, v1.w);
        }
        if (m >= 2 && m <= 65) {
            const float a2 = bcast_lane(wgt[2], m - 2);
            v2.x = fmaf(a2, xv.x, v2.x); v2.y = fmaf(a2, xv.y, v2.y);
            v2.z = fmaf(a2, xv.z, v2.z); v2.w = fmaf(a2, xv.w, v2.w);
        }
        if (m >= 3) {
            const float a3 = bcast_lane(wgt[3], m - 3);
            v3.x = fmaf(a3, xv.x, v3.x); v3.y = fmaf(a3, xv.y, v3.y);
            v3.z = fmaf(a3, xv.z, v3.z); v3.w = fmaf(a3, xv.w, v3.w);
        }
    }

    float* ob = out + (size_t)(b * T + tq) * D + dh * (D / 2);
    ((float4*)(ob + 0 * D))[lane] = v0;
    ((float4*)(ob + 1 * D))[lane] = v1;
    ((float4*)(ob + 2 * D))[lane] = v2;
    ((float4*)(ob + 3 * D))[lane] = v3;
}

extern "C" void kernel_launch(void* const* d_in, const int* in_sizes, int n_in,
                              void* d_out, int out_size, void* d_ws, size_t ws_size,
                              hipStream_t stream)
{
    const float* x  = (const float*)d_in[0];
    const float* Wt = (const float*)d_in[1];
    const float* Wx = (const float*)d_in[2];
    const float* bh = (const float*)d_in[3];
    const float* Wa = (const float*)d_in[4];
    const float* ba = (const float*)d_in[5];
    float* out = (float*)d_out;
    float* qk  = (float*)d_ws;   // B*T*64 floats = 1 MB

    qk_kernel<<<dim3(256), dim3(512), 0, stream>>>(x, Wt, Wx, bh, qk);
    attn_kernel<<<dim3(256), dim3(512), 0, stream>>>(x, qk, Wa, ba, out);
}